// Round 4
// baseline (148.007 us; speedup 1.0000x reference)
//
#include <hip/hip_runtime.h>
#include <stdint.h>

// FP4 quant-dequant, faithful to the JAX reference in float32 arithmetic.
// v4: two stream-ordered kernels (no cooperative launch).
//   k_scales: per-thread block of 64 -> 95th-pct scale, quantize in-register,
//             store packed int8 levels (4*level) + scale; atomic global
//             min/max of scales into hdr (uint-encoded positive floats).
//   k_deq:    coalesced read of packed levels, per-thread double-quantized
//             scale, write dequantized output.
// hdr init via two 4-byte hipMemsetAsync (graph-capture safe).

#define BLK 64
#define WG 256
#define FLT_BIG 3.402823466e+38f

// Branchless insert of `a` into descending-sorted top-5 register array.
__device__ __forceinline__ void ins5(float (&t)[5], float a) {
#pragma unroll
    for (int k = 0; k < 4; ++k) {
        float m = fmaxf(t[k], a);
        a = fminf(t[k], a);
        t[k] = m;
    }
    t[4] = fmaxf(t[4], a);
}

// 4 * nearest FP4 level via boundary ladder (integers, exact).
// Equivalent to first-index argmin over the FP4 table: midpoints are exact
// dyadics; midpoint ties go to the lower-index level in both formulations.
__device__ __forceinline__ int qlvl4(float xn) {
    int bv = -12;
    bv += (xn > -2.5f)   ? 4 : 0;
    bv += (xn > -1.75f)  ? 2 : 0;
    bv += (xn > -1.25f)  ? 2 : 0;
    bv += (xn > -0.875f) ? 1 : 0;
    bv += (xn > -0.375f) ? 3 : 0;
    bv += (xn > 0.375f)  ? 3 : 0;
    bv += (xn > 0.875f)  ? 1 : 0;
    bv += (xn > 1.25f)   ? 2 : 0;
    bv += (xn > 1.75f)   ? 2 : 0;
    bv += (xn > 2.5f)    ? 4 : 0;
    return bv;
}

// Double-quantized scale, pre-divided by 4 (pairs with 4*level levels; the
// /4 and *4 are exact power-of-two scalings => bit-identical to lvl*ds).
__device__ __forceinline__ float dscale4(float s, float smin, float smax) {
    if (smax > smin) {
        const float ss = __fdiv_rn(__fsub_rn(smax, smin), 255.0f);
        float q = rintf(__fdiv_rn(__fsub_rn(s, smin), ss));   // round half-even
        q = fminf(fmaxf(q, 0.0f), 255.0f);                    // clip AFTER round
        return __fmul_rn(q, ss) * 0.25f;
    }
    return 0.0f;   // q=0, scale_scale=1 -> deq 0
}

template <bool STORE_LEVELS>
__global__ __launch_bounds__(WG, 4) void k_scales(const float* __restrict__ x,
                                                  int n, int nblocks,
                                                  float* __restrict__ scales,
                                                  uint32_t* __restrict__ levels,
                                                  uint32_t* __restrict__ hdr) {
    const int b = blockIdx.x * WG + threadIdx.x;
    const bool valid = (b < nblocks);
    const int base = b * BLK;

    float s = 0.0f;
    if (valid) {
        float4 v[16];
        if (base + BLK <= n) {
            const float4* x4 = reinterpret_cast<const float4*>(x + base);
#pragma unroll
            for (int j = 0; j < 16; ++j) v[j] = x4[j];
        } else {
            for (int j = 0; j < 16; ++j) {
                float tmp[4];
                for (int k = 0; k < 4; ++k) {
                    int idx = base + j * 4 + k;
                    tmp[k] = (idx < n) ? x[idx] : 0.0f;  // reference zero-pads
                }
                v[j] = make_float4(tmp[0], tmp[1], tmp[2], tmp[3]);
            }
        }
        // Two independent insertion chains for ILP; abs>=0 so 0-init is safe.
        float A[5] = {0.f, 0.f, 0.f, 0.f, 0.f};
        float B[5] = {0.f, 0.f, 0.f, 0.f, 0.f};
#pragma unroll
        for (int j = 0; j < 16; j += 2) {
            ins5(A, fabsf(v[j].x));     ins5(B, fabsf(v[j + 1].x));
            ins5(A, fabsf(v[j].y));     ins5(B, fabsf(v[j + 1].y));
            ins5(A, fabsf(v[j].z));     ins5(B, fabsf(v[j + 1].z));
            ins5(A, fabsf(v[j].w));     ins5(B, fabsf(v[j + 1].w));
        }
#pragma unroll
        for (int k = 0; k < 5; ++k) ins5(A, B[k]);

        // JAX f32 quantile: q = 0.95f*63.0f; result = v59*lw + v60*hw
        const float qs = 0.95f * 63.0f;     // 59.849998474121094f
        const float hw = qs - 59.0f;
        const float lw = 60.0f - qs;
        s = __fadd_rn(__fmul_rn(A[4], lw), __fmul_rn(A[3], hw));
        s = fmaxf(s, 1e-8f);
        scales[b] = s;

        if (STORE_LEVELS) {
            uint32_t* lp = levels + (size_t)b * 16;
#pragma unroll
            for (int j = 0; j < 16; ++j) {
                int a0 = qlvl4(__fdiv_rn(v[j].x, s));
                int a1 = qlvl4(__fdiv_rn(v[j].y, s));
                int a2 = qlvl4(__fdiv_rn(v[j].z, s));
                int a3 = qlvl4(__fdiv_rn(v[j].w, s));
                lp[j] = (uint32_t)(a0 & 255) | ((uint32_t)(a1 & 255) << 8) |
                        ((uint32_t)(a2 & 255) << 16) | ((uint32_t)(a3 & 255) << 24);
            }
        }
    }

    // WG min/max reduce, then one atomicMin/Max per WG (uint order == float
    // order for positive floats; s >= 1e-8 > 0 always).
    float mn = valid ? s : FLT_BIG;
    float mx = valid ? s : 0.0f;
#pragma unroll
    for (int off = 32; off > 0; off >>= 1) {
        mn = fminf(mn, __shfl_xor(mn, off, 64));
        mx = fmaxf(mx, __shfl_xor(mx, off, 64));
    }
    __shared__ float smn[4], smx[4];
    const int lane = threadIdx.x & 63, w = threadIdx.x >> 6;
    if (lane == 0) { smn[w] = mn; smx[w] = mx; }
    __syncthreads();
    if (threadIdx.x == 0) {
        float fmn = smn[0], fmx = smx[0];
#pragma unroll
        for (int i = 1; i < 4; ++i) { fmn = fminf(fmn, smn[i]); fmx = fmaxf(fmx, smx[i]); }
        atomicMin(&hdr[0], __float_as_uint(fmn));
        atomicMax(&hdr[1], __float_as_uint(fmx));
    }
}

__global__ __launch_bounds__(WG) void k_deq(const uint32_t* __restrict__ levels,
                                            const float* __restrict__ scales,
                                            const uint32_t* __restrict__ hdr,
                                            int n, int nwords,
                                            float* __restrict__ out) {
    const int t = blockIdx.x * WG + threadIdx.x;
    if (t >= nwords) return;
    const float smin = __uint_as_float(hdr[0]);
    const float smax = __uint_as_float(hdr[1]);
    const float s = scales[t >> 4];
    const float ds4 = dscale4(s, smin, smax);

    const uint32_t wv = levels[t];
    const int i = t * 4;
    if (i + 3 < n) {
        float4 ov;
        ov.x = __fmul_rn((float)(int)(int8_t)(wv), ds4);
        ov.y = __fmul_rn((float)(int)(int8_t)(wv >> 8), ds4);
        ov.z = __fmul_rn((float)(int)(int8_t)(wv >> 16), ds4);
        ov.w = __fmul_rn((float)(int)(int8_t)(wv >> 24), ds4);
        *reinterpret_cast<float4*>(out + i) = ov;
    } else {
        for (int k = 0; k < 4 && i + k < n; ++k)
            out[i + k] = __fmul_rn((float)(int)(int8_t)(wv >> (8 * k)), ds4);
    }
}

// Fallback if ws can't hold the levels array: re-quantize from x.
__global__ __launch_bounds__(WG) void k_quant(const float* __restrict__ x,
                                              const float* __restrict__ scales,
                                              const uint32_t* __restrict__ hdr,
                                              int n,
                                              float* __restrict__ out) {
    const int t = blockIdx.x * WG + threadIdx.x;
    const int i = t * 4;
    if (i >= n) return;
    const float smin = __uint_as_float(hdr[0]);
    const float smax = __uint_as_float(hdr[1]);
    const float s = scales[i >> 6];
    const float ds4 = dscale4(s, smin, smax);

    if (i + 3 < n) {
        const float4 xv = *reinterpret_cast<const float4*>(x + i);
        float4 ov;
        ov.x = __fmul_rn((float)qlvl4(__fdiv_rn(xv.x, s)), ds4);
        ov.y = __fmul_rn((float)qlvl4(__fdiv_rn(xv.y, s)), ds4);
        ov.z = __fmul_rn((float)qlvl4(__fdiv_rn(xv.z, s)), ds4);
        ov.w = __fmul_rn((float)qlvl4(__fdiv_rn(xv.w, s)), ds4);
        *reinterpret_cast<float4*>(out + i) = ov;
    } else {
        for (int j = 0; j < 4 && i + j < n; ++j)
            out[i + j] = __fmul_rn((float)qlvl4(__fdiv_rn(x[i + j], s)), ds4);
    }
}

extern "C" void kernel_launch(void* const* d_in, const int* in_sizes, int n_in,
                              void* d_out, int out_size, void* d_ws, size_t ws_size,
                              hipStream_t stream) {
    const float* x = (const float*)d_in[0];
    float* out = (float*)d_out;
    const int n = in_sizes[0];
    const int nblocks = (n + BLK - 1) / BLK;
    const int nwords = nblocks * 16;                 // packed u32 words
    const int nwgScales = (nblocks + WG - 1) / WG;

    // ws layout: [hdr: 2 u32, padded to 16B] [scales: nblocks f32] [levels]
    uint32_t* hdr = (uint32_t*)d_ws;
    float* scales = (float*)((char*)d_ws + 16);
    uint32_t* levels = (uint32_t*)(scales + nblocks);
    const size_t need = 16 + (size_t)nblocks * 4 + (size_t)nwords * 4;
    const bool useLevels = (ws_size >= need);

    // hdr[0]=min init 0xFFFFFFFF (uint-max), hdr[1]=max init 0.
    hipMemsetAsync((void*)hdr, 0xFF, 4, stream);
    hipMemsetAsync((void*)((char*)d_ws + 4), 0x00, 4, stream);

    if (useLevels) {
        k_scales<true><<<nwgScales, WG, 0, stream>>>(x, n, nblocks, scales, levels, hdr);
        k_deq<<<(nwords + WG - 1) / WG, WG, 0, stream>>>(levels, scales, hdr, n, nwords, out);
    } else {
        k_scales<false><<<nwgScales, WG, 0, stream>>>(x, n, nblocks, scales, levels, hdr);
        k_quant<<<((n + 3) / 4 + WG - 1) / WG, WG, 0, stream>>>(x, scales, hdr, n, out);
    }
}

// Round 5
// 144.318 us; speedup vs baseline: 1.0256x; 1.0256x over previous
//
#include <hip/hip_runtime.h>
#include <stdint.h>

// FP4 quant-dequant, faithful to the JAX reference in float32 arithmetic.
// v5: k_scales stages x through XOR-swizzled LDS so ALL global traffic is
// lane-contiguous (loads, scale stores, packed-level stores); per-thread
// block math unchanged. k_deq unchanged (coalesced).

#define BLK 64
#define WG 256
#define FLT_BIG 3.402823466e+38f

// Branchless insert of `a` into descending-sorted top-5 register array.
__device__ __forceinline__ void ins5(float (&t)[5], float a) {
#pragma unroll
    for (int k = 0; k < 4; ++k) {
        float m = fmaxf(t[k], a);
        a = fminf(t[k], a);
        t[k] = m;
    }
    t[4] = fmaxf(t[4], a);
}

// 4 * nearest FP4 level via boundary ladder (integers, exact).
// Equivalent to first-index argmin over the FP4 table: midpoints are exact
// dyadics; midpoint ties go to the lower-index level in both formulations.
__device__ __forceinline__ int qlvl4(float xn) {
    int bv = -12;
    bv += (xn > -2.5f)   ? 4 : 0;
    bv += (xn > -1.75f)  ? 2 : 0;
    bv += (xn > -1.25f)  ? 2 : 0;
    bv += (xn > -0.875f) ? 1 : 0;
    bv += (xn > -0.375f) ? 3 : 0;
    bv += (xn > 0.375f)  ? 3 : 0;
    bv += (xn > 0.875f)  ? 1 : 0;
    bv += (xn > 1.25f)   ? 2 : 0;
    bv += (xn > 1.75f)   ? 2 : 0;
    bv += (xn > 2.5f)    ? 4 : 0;
    return bv;
}

// Double-quantized scale, pre-divided by 4 (pairs with 4*level; /4 and *4 are
// exact power-of-two scalings => bit-identical to lvl*ds).
__device__ __forceinline__ float dscale4(float s, float smin, float smax) {
    if (smax > smin) {
        const float ss = __fdiv_rn(__fsub_rn(smax, smin), 255.0f);
        float q = rintf(__fdiv_rn(__fsub_rn(s, smin), ss));   // round half-even
        q = fminf(fmaxf(q, 0.0f), 255.0f);                    // clip AFTER round
        return __fmul_rn(q, ss) * 0.25f;
    }
    return 0.0f;   // q=0, scale_scale=1 -> deq 0
}

template <bool STORE_LEVELS>
__global__ __launch_bounds__(WG, 2) void k_scales(const float* __restrict__ x,
                                                  int n, int nblocks, int nwords,
                                                  float* __restrict__ scales,
                                                  uint32_t* __restrict__ levels,
                                                  uint32_t* __restrict__ hdr) {
    // 64 KB: one 16 KB (1024-float4) slice per wave. XOR-swizzled rows:
    // block b float4 j lives at slice[b*16 + (j ^ (b&15))] -> both the
    // coalesced-write phase and per-lane row-read phase spread evenly
    // across all 32 banks (<=2 lanes/bank, free).
    __shared__ float4 ldsAll[4 * 1024];
    const int lane = threadIdx.x & 63;
    const int wv = threadIdx.x >> 6;
    float4* L = ldsAll + wv * 1024;

    const int waveBlockBase = (blockIdx.x * 4 + wv) * 64;
    const bool waveActive = (waveBlockBase < nblocks);
    const long eBase = (long)waveBlockBase * BLK;
    const int myB = waveBlockBase + lane;
    const bool valid = (myB < nblocks);

    // ---- Phase A: coalesced global -> swizzled LDS ----
    if (waveActive) {
        if (eBase + 4096 <= (long)n) {
            const float4* x4 = reinterpret_cast<const float4*>(x + eBase);
#pragma unroll
            for (int s = 0; s < 16; ++s) {
                const int idx = s * 64 + lane;
                const float4 g = x4[idx];
                const int b = idx >> 4, j = idx & 15;
                L[b * 16 + (j ^ (b & 15))] = g;
            }
        } else {
            for (int s = 0; s < 16; ++s) {
                const int idx = s * 64 + lane;
                float tmp[4];
                for (int d = 0; d < 4; ++d) {
                    const long gi = eBase + (long)idx * 4 + d;
                    tmp[d] = (gi < (long)n) ? x[gi] : 0.0f;  // reference zero-pads
                }
                const int b = idx >> 4, j = idx & 15;
                L[b * 16 + (j ^ (b & 15))] = make_float4(tmp[0], tmp[1], tmp[2], tmp[3]);
            }
        }
    }
    __syncthreads();

    // ---- Phase B: per-lane block math (unchanged vs v4) ----
    float s = 0.0f;
    uint32_t plv[16];
    if (valid) {
        float4 v[16];
#pragma unroll
        for (int j = 0; j < 16; ++j)
            v[j] = L[lane * 16 + (j ^ (lane & 15))];

        float A[5] = {0.f, 0.f, 0.f, 0.f, 0.f};
        float B[5] = {0.f, 0.f, 0.f, 0.f, 0.f};
#pragma unroll
        for (int j = 0; j < 16; j += 2) {
            ins5(A, fabsf(v[j].x));     ins5(B, fabsf(v[j + 1].x));
            ins5(A, fabsf(v[j].y));     ins5(B, fabsf(v[j + 1].y));
            ins5(A, fabsf(v[j].z));     ins5(B, fabsf(v[j + 1].z));
            ins5(A, fabsf(v[j].w));     ins5(B, fabsf(v[j + 1].w));
        }
#pragma unroll
        for (int k = 0; k < 5; ++k) ins5(A, B[k]);

        // JAX f32 quantile: q = 0.95f*63.0f; result = v59*lw + v60*hw
        const float qs = 0.95f * 63.0f;     // 59.849998474121094f
        const float hw = qs - 59.0f;
        const float lw = 60.0f - qs;
        s = __fadd_rn(__fmul_rn(A[4], lw), __fmul_rn(A[3], hw));
        s = fmaxf(s, 1e-8f);
        scales[myB] = s;   // lane-contiguous, coalesced

        if (STORE_LEVELS) {
#pragma unroll
            for (int j = 0; j < 16; ++j) {
                const int a0 = qlvl4(__fdiv_rn(v[j].x, s));
                const int a1 = qlvl4(__fdiv_rn(v[j].y, s));
                const int a2 = qlvl4(__fdiv_rn(v[j].z, s));
                const int a3 = qlvl4(__fdiv_rn(v[j].w, s));
                plv[j] = (uint32_t)(a0 & 255) | ((uint32_t)(a1 & 255) << 8) |
                         ((uint32_t)(a2 & 255) << 16) | ((uint32_t)(a3 & 255) << 24);
            }
        }
    }
    __syncthreads();

    // ---- Phase C: levels -> swizzled LDS -> coalesced uint4 stores ----
    if (STORE_LEVELS && waveActive) {
        uint32_t* Lu = reinterpret_cast<uint32_t*>(L);
        if (valid) {
#pragma unroll
            for (int j = 0; j < 16; ++j)
                Lu[lane * 16 + (j ^ (lane & 15))] = plv[j];
        }
        const int wordBase = waveBlockBase * 16;
#pragma unroll
        for (int m = 0; m < 4; ++m) {
            const int widx = m * 256 + lane * 4;
            uint32_t w[4];
#pragma unroll
            for (int d = 0; d < 4; ++d) {
                const int lw = widx + d;
                const int b = lw >> 4, j = lw & 15;
                w[d] = Lu[b * 16 + (j ^ (b & 15))];
            }
            if (wordBase + widx + 3 < nwords) {
                *reinterpret_cast<uint4*>(levels + wordBase + widx) =
                    make_uint4(w[0], w[1], w[2], w[3]);
            } else {
                for (int d = 0; d < 4; ++d)
                    if (wordBase + widx + d < nwords) levels[wordBase + widx + d] = w[d];
            }
        }
    }

    // ---- Phase D: WG min/max of s -> atomics (reuse big LDS) ----
    float mn = valid ? s : FLT_BIG;
    float mx = valid ? s : 0.0f;
#pragma unroll
    for (int off = 32; off > 0; off >>= 1) {
        mn = fminf(mn, __shfl_xor(mn, off, 64));
        mx = fmaxf(mx, __shfl_xor(mx, off, 64));
    }
    __syncthreads();                 // Phase C LDS reads done before reuse
    float* red = reinterpret_cast<float*>(ldsAll);
    if (lane == 0) { red[wv] = mn; red[4 + wv] = mx; }
    __syncthreads();
    if (threadIdx.x == 0) {
        float fmn = red[0], fmx = red[4];
#pragma unroll
        for (int i = 1; i < 4; ++i) { fmn = fminf(fmn, red[i]); fmx = fmaxf(fmx, red[4 + i]); }
        // uint order == float order for positive floats; s >= 1e-8 > 0.
        atomicMin(&hdr[0], __float_as_uint(fmn));
        atomicMax(&hdr[1], __float_as_uint(fmx));
    }
}

__global__ __launch_bounds__(WG) void k_deq(const uint32_t* __restrict__ levels,
                                            const float* __restrict__ scales,
                                            const uint32_t* __restrict__ hdr,
                                            int n, int nwords,
                                            float* __restrict__ out) {
    const int t = blockIdx.x * WG + threadIdx.x;
    if (t >= nwords) return;
    const float smin = __uint_as_float(hdr[0]);
    const float smax = __uint_as_float(hdr[1]);
    const float s = scales[t >> 4];
    const float ds4 = dscale4(s, smin, smax);

    const uint32_t wv = levels[t];
    const int i = t * 4;
    if (i + 3 < n) {
        float4 ov;
        ov.x = __fmul_rn((float)(int)(int8_t)(wv), ds4);
        ov.y = __fmul_rn((float)(int)(int8_t)(wv >> 8), ds4);
        ov.z = __fmul_rn((float)(int)(int8_t)(wv >> 16), ds4);
        ov.w = __fmul_rn((float)(int)(int8_t)(wv >> 24), ds4);
        *reinterpret_cast<float4*>(out + i) = ov;
    } else {
        for (int k = 0; k < 4 && i + k < n; ++k)
            out[i + k] = __fmul_rn((float)(int)(int8_t)(wv >> (8 * k)), ds4);
    }
}

// Fallback if ws can't hold the levels array: re-quantize from x.
__global__ __launch_bounds__(WG) void k_quant(const float* __restrict__ x,
                                              const float* __restrict__ scales,
                                              const uint32_t* __restrict__ hdr,
                                              int n,
                                              float* __restrict__ out) {
    const int t = blockIdx.x * WG + threadIdx.x;
    const int i = t * 4;
    if (i >= n) return;
    const float smin = __uint_as_float(hdr[0]);
    const float smax = __uint_as_float(hdr[1]);
    const float s = scales[i >> 6];
    const float ds4 = dscale4(s, smin, smax);

    if (i + 3 < n) {
        const float4 xv = *reinterpret_cast<const float4*>(x + i);
        float4 ov;
        ov.x = __fmul_rn((float)qlvl4(__fdiv_rn(xv.x, s)), ds4);
        ov.y = __fmul_rn((float)qlvl4(__fdiv_rn(xv.y, s)), ds4);
        ov.z = __fmul_rn((float)qlvl4(__fdiv_rn(xv.z, s)), ds4);
        ov.w = __fmul_rn((float)qlvl4(__fdiv_rn(xv.w, s)), ds4);
        *reinterpret_cast<float4*>(out + i) = ov;
    } else {
        for (int j = 0; j < 4 && i + j < n; ++j)
            out[i + j] = __fmul_rn((float)qlvl4(__fdiv_rn(x[i + j], s)), ds4);
    }
}

extern "C" void kernel_launch(void* const* d_in, const int* in_sizes, int n_in,
                              void* d_out, int out_size, void* d_ws, size_t ws_size,
                              hipStream_t stream) {
    const float* x = (const float*)d_in[0];
    float* out = (float*)d_out;
    const int n = in_sizes[0];
    const int nblocks = (n + BLK - 1) / BLK;
    const int nwords = nblocks * 16;                       // packed u32 words
    const int nwgScales = (nblocks + 255) / 256;           // 256 blocks per WG

    // ws layout: [hdr: 2 u32, padded to 16B] [scales: nblocks f32] [levels]
    uint32_t* hdr = (uint32_t*)d_ws;
    float* scales = (float*)((char*)d_ws + 16);
    uint32_t* levels = (uint32_t*)(scales + nblocks);
    const size_t need = 16 + (size_t)nblocks * 4 + (size_t)nwords * 4;
    const bool useLevels = (ws_size >= need);

    // hdr[0]=min init 0xFFFFFFFF (uint-max), hdr[1]=max init 0.
    hipMemsetAsync((void*)hdr, 0xFF, 4, stream);
    hipMemsetAsync((void*)((char*)d_ws + 4), 0x00, 4, stream);

    if (useLevels) {
        k_scales<true><<<nwgScales, WG, 0, stream>>>(x, n, nblocks, nwords, scales, levels, hdr);
        k_deq<<<(nwords + WG - 1) / WG, WG, 0, stream>>>(levels, scales, hdr, n, nwords, out);
    } else {
        k_scales<false><<<nwgScales, WG, 0, stream>>>(x, n, nblocks, nwords, scales, levels, hdr);
        k_quant<<<((n + 3) / 4 + WG - 1) / WG, WG, 0, stream>>>(x, scales, hdr, n, out);
    }
}